// Round 2
// baseline (397.519 us; speedup 1.0000x reference)
//
#include <hip/hip_runtime.h>

#define B_ROWS 262144
#define TPB 256
#define NBLK 512   // B_ROWS / (TPB * 2)

__device__ __forceinline__ float fast_tanh(float x) {
    float e = __expf(2.0f * x);
    return 1.0f - 2.0f * __builtin_amdgcn_rcpf(e + 1.0f);
}

// ---------------------------------------------------------------------------
// Kernel 1: partial sums (sum, sumsq per dim) of x -> part[16][NBLK]
// ---------------------------------------------------------------------------
__global__ void __launch_bounds__(TPB)
init_partials(const float* __restrict__ x, float* __restrict__ part)
{
    const int tid  = threadIdx.x;
    const int bid  = blockIdx.x;
    const int lane = tid & 63;
    const int wid  = tid >> 6;
    const size_t r0 = (size_t)bid * (TPB * 2) + tid;
    const size_t r1 = r0 + TPB;

    __shared__ float lred[64];

    const float4* p0 = reinterpret_cast<const float4*>(x + r0 * 8);
    const float4* p1 = reinterpret_cast<const float4*>(x + r1 * 8);
    float4 a = p0[0], b4 = p0[1], c = p1[0], d4 = p1[1];
    float z0[8] = {a.x, a.y, a.z, a.w, b4.x, b4.y, b4.z, b4.w};
    float z1[8] = {c.x, c.y, c.z, c.w, d4.x, d4.y, d4.z, d4.w};

    float acc[16];
    #pragma unroll
    for (int j = 0; j < 8; ++j) {
        acc[j]     = z0[j] + z1[j];
        acc[8 + j] = z0[j] * z0[j] + z1[j] * z1[j];
    }
    #pragma unroll
    for (int d = 1; d < 64; d <<= 1) {
        #pragma unroll
        for (int j = 0; j < 16; ++j) acc[j] += __shfl_xor(acc[j], d, 64);
    }
    if (lane == 0) {
        #pragma unroll
        for (int j = 0; j < 16; ++j) lred[wid * 16 + j] = acc[j];
    }
    __syncthreads();
    if (tid < 16) {
        float s = lred[tid] + lred[16 + tid] + lred[32 + tid] + lred[48 + tid];
        part[tid * NBLK + bid] = s;
    }
}

// ---------------------------------------------------------------------------
// Kernel 2: one flow layer. Redundant per-block stats reduce -> actnorm ->
// MLP -> coupling epilogue -> write z/ld, emit next-layer partials.
// ---------------------------------------------------------------------------
__global__ void __launch_bounds__(TPB)
layer_apply(const int L, const int last,
            const float* __restrict__ zin,  const float* __restrict__ ldin,
            float* __restrict__ zout,       float* __restrict__ ldout,
            const float* __restrict__ pin,  float* __restrict__ pout,
            const float* __restrict__ bvec, const float* __restrict__ logs,
            const float* __restrict__ log_gamma,
            const float* __restrict__ W1,   const float* __restrict__ b1,
            const float* __restrict__ W2,   const float* __restrict__ b2,
            const float* __restrict__ Wf,   const float* __restrict__ bf)
{
    const int tid  = threadIdx.x;
    const int bid  = blockIdx.x;
    const int lane = tid & 63;
    const int wid  = tid >> 6;
    const size_t r0 = (size_t)bid * (TPB * 2) + tid;
    const size_t r1 = r0 + TPB;

    __shared__ float lred[64];

    // ---- stats: every block redundantly reduces the 16 x NBLK partials ----
    float tot[16];
    {
        float a16[16];
        #pragma unroll
        for (int j = 0; j < 16; ++j)
            a16[j] = pin[j * NBLK + tid] + pin[j * NBLK + TPB + tid];
        #pragma unroll
        for (int d = 1; d < 64; d <<= 1) {
            #pragma unroll
            for (int j = 0; j < 16; ++j) a16[j] += __shfl_xor(a16[j], d, 64);
        }
        if (lane == 0) {
            #pragma unroll
            for (int j = 0; j < 16; ++j) lred[wid * 16 + j] = a16[j];
        }
        __syncthreads();
        #pragma unroll
        for (int j = 0; j < 16; ++j)
            tot[j] = lred[j] + lred[16 + j] + lred[32 + j] + lred[48 + j];
        __syncthreads();   // everyone done reading lred before epilogue reuses it
    }

    const float invB = 1.0f / (float)B_ROWS;
    float es[8], beta[8];
    float sum_s = 0.f;
    #pragma unroll
    for (int j = 0; j < 8; ++j) {
        float m = tot[j] * invB;
        float q = tot[8 + j] * invB;
        float v = q - m * m;
        v = v < 0.f ? 0.f : v;
        float li = -(1.0f / 3.0f) * __logf(sqrtf(v) + 1e-6f);
        float s = logs[L * 8 + j] + li;
        s = s < -5.f ? -5.f : (s > 5.f ? 5.f : s);
        es[j]   = __expf(s);
        beta[j] = bvec[L * 8 + j] - m;
        sum_s  += s;
    }
    float gfac[4];
    #pragma unroll
    for (int j = 0; j < 4; ++j) {
        float lg = log_gamma[L * 4 + j];
        lg = lg < -5.f ? -5.f : (lg > 5.f ? 5.f : lg);
        gfac[j] = __expf(lg);
    }

    // ---- load 2 rows, actnorm ----
    float z[2][8];
    {
        const float4* p0 = reinterpret_cast<const float4*>(zin + r0 * 8);
        const float4* p1 = reinterpret_cast<const float4*>(zin + r1 * 8);
        float4 a = p0[0], c = p0[1];
        z[0][0]=a.x; z[0][1]=a.y; z[0][2]=a.z; z[0][3]=a.w;
        z[0][4]=c.x; z[0][5]=c.y; z[0][6]=c.z; z[0][7]=c.w;
        a = p1[0]; c = p1[1];
        z[1][0]=a.x; z[1][1]=a.y; z[1][2]=a.z; z[1][3]=a.w;
        z[1][4]=c.x; z[1][5]=c.y; z[1][6]=c.z; z[1][7]=c.w;
    }
    #pragma unroll
    for (int r = 0; r < 2; ++r)
        #pragma unroll
        for (int j = 0; j < 8; ++j)
            z[r][j] = (z[r][j] + beta[j]) * es[j];

    // ---- MLP (weights are uniform-address -> SGPR loads) ----
    const float* w1  = W1 + L * (4 * 32);
    const float* w2  = W2 + L * (32 * 32);
    const float* wf  = Wf + L * (32 * 8);
    const float* vb1 = b1 + L * 32;
    const float* vb2 = b2 + L * 32;
    const float* vbf = bf + L * 8;

    float h1a[32], h1b[32];
    #pragma unroll
    for (int w = 0; w < 32; ++w) {
        float bw = vb1[w];
        float ta = bw, tb = bw;
        #pragma unroll
        for (int k = 0; k < 4; ++k) {
            float wv = w1[k * 32 + w];
            ta += z[0][k] * wv;
            tb += z[1][k] * wv;
        }
        h1a[w] = ta > 0.f ? ta : 0.f;
        h1b[w] = tb > 0.f ? tb : 0.f;
    }

    float h2a[32], h2b[32];
    #pragma unroll
    for (int w = 0; w < 32; ++w) { float bw = vb2[w]; h2a[w] = bw; h2b[w] = bw; }
    #pragma unroll
    for (int k = 0; k < 32; ++k) {
        float va = h1a[k], vb = h1b[k];
        #pragma unroll
        for (int w = 0; w < 32; ++w) {
            float wv = w2[k * 32 + w];
            h2a[w] += va * wv;
            h2b[w] += vb * wv;
        }
    }
    #pragma unroll
    for (int w = 0; w < 32; ++w) {
        h2a[w] = h2a[w] > 0.f ? h2a[w] : 0.f;
        h2b[w] = h2b[w] > 0.f ? h2b[w] : 0.f;
    }

    float h3a[8], h3b[8];
    #pragma unroll
    for (int j = 0; j < 8; ++j) { float bw = vbf[j]; h3a[j] = bw; h3b[j] = bw; }
    #pragma unroll
    for (int k = 0; k < 32; ++k) {
        float va = h2a[k], vb = h2b[k];
        #pragma unroll
        for (int j = 0; j < 8; ++j) {
            float wv = wf[k * 8 + j];
            h3a[j] += va * wv;
            h3b[j] += vb * wv;
        }
    }

    // ---- coupling epilogue + permutation + next-layer partials ----
    float nacc[16];
    #pragma unroll
    for (int j = 0; j < 16; ++j) nacc[j] = 0.f;

    float ldv[2] = { ldin[r0], ldin[r1] };
    #pragma unroll
    for (int r = 0; r < 2; ++r) {
        const float* H = (r == 0) ? h3a : h3b;
        float ldl = 0.f;
        float nz[8];
        #pragma unroll
        for (int j = 0; j < 4; ++j) {
            float sc = 0.6f * fast_tanh(H[2 * j + 1]);
            float sh = gfac[j] * fast_tanh(H[2 * j]);
            float z2 = z[r][4 + j];
            z2 = z2 + sc * z2 + sh;
            ldl += __logf(1.0f + sc);
            nz[3 - j] = z2;        // reversed: out[3-j] = z2_j
            nz[7 - j] = z[r][j];   // reversed: out[7-j] = z1_j
        }
        ldv[r] += sum_s + ldl;
        #pragma unroll
        for (int j = 0; j < 8; ++j) {
            z[r][j] = nz[j];
            nacc[j]     += nz[j];
            nacc[8 + j] += nz[j] * nz[j];
        }
    }

    // ---- store z / ld ----
    {
        float4* p0 = reinterpret_cast<float4*>(zout + r0 * 8);
        float4* p1 = reinterpret_cast<float4*>(zout + r1 * 8);
        float4 a, c;
        a.x=z[0][0]; a.y=z[0][1]; a.z=z[0][2]; a.w=z[0][3];
        c.x=z[0][4]; c.y=z[0][5]; c.z=z[0][6]; c.w=z[0][7];
        p0[0] = a; p0[1] = c;
        a.x=z[1][0]; a.y=z[1][1]; a.z=z[1][2]; a.w=z[1][3];
        c.x=z[1][4]; c.y=z[1][5]; c.z=z[1][6]; c.w=z[1][7];
        p1[0] = a; p1[1] = c;
    }
    ldout[r0] = ldv[0];
    ldout[r1] = ldv[1];

    if (!last) {
        #pragma unroll
        for (int d = 1; d < 64; d <<= 1) {
            #pragma unroll
            for (int j = 0; j < 16; ++j) nacc[j] += __shfl_xor(nacc[j], d, 64);
        }
        if (lane == 0) {
            #pragma unroll
            for (int j = 0; j < 16; ++j) lred[wid * 16 + j] = nacc[j];
        }
        __syncthreads();
        if (tid < 16) {
            float s = lred[tid] + lred[16 + tid] + lred[32 + tid] + lred[48 + tid];
            pout[tid * NBLK + bid] = s;
        }
    }
}

extern "C" void kernel_launch(void* const* d_in, const int* in_sizes, int n_in,
                              void* d_out, int out_size, void* d_ws, size_t ws_size,
                              hipStream_t stream) {
    const float* x      = (const float*)d_in[0];
    const float* logdet = (const float*)d_in[1];
    const float* bvec   = (const float*)d_in[2];
    const float* logs   = (const float*)d_in[3];
    const float* lg     = (const float*)d_in[4];
    const float* W1     = (const float*)d_in[5];
    const float* b1     = (const float*)d_in[6];
    const float* W2     = (const float*)d_in[7];
    const float* b2     = (const float*)d_in[8];
    const float* Wf     = (const float*)d_in[9];
    const float* bf     = (const float*)d_in[10];
    float* out = (float*)d_out;

    // workspace layout (floats): zA[B*8] | ldA[B] | part0[16*NBLK] | part1[16*NBLK]
    float* zA    = (float*)d_ws;
    float* ldA   = zA  + (size_t)B_ROWS * 8;
    float* part0 = ldA + B_ROWS;
    float* part1 = part0 + 16 * NBLK;

    float* out_z  = out;
    float* out_ld = out + (size_t)B_ROWS * 8;

    init_partials<<<NBLK, TPB, 0, stream>>>(x, part0);

    const float* zi  = x;
    const float* ldi = logdet;
    float* pbuf[2] = { part0, part1 };
    int buf = 0;
    for (int L = 0; L < 8; ++L) {
        float* zo  = (L & 1) ? out_z  : zA;    // L7 (odd) lands in out
        float* ldo = (L & 1) ? out_ld : ldA;
        int last = (L == 7);
        layer_apply<<<NBLK, TPB, 0, stream>>>(
            L, last, zi, ldi, zo, ldo, pbuf[buf], pbuf[buf ^ 1],
            bvec, logs, lg, W1, b1, W2, b2, Wf, bf);
        zi = zo; ldi = ldo; buf ^= 1;
    }
}

// Round 3
// 269.914 us; speedup vs baseline: 1.4728x; 1.4728x over previous
//
#include <hip/hip_runtime.h>

#define B_ROWS 262144
#define TPB 256
#define NBLK 1024   // B_ROWS / TPB, 1 row per thread

__device__ __forceinline__ float fast_tanh(float x) {
    float e = __expf(2.0f * x);
    return 1.0f - 2.0f * __builtin_amdgcn_rcpf(e + 1.0f);
}

// ---------------------------------------------------------------------------
// Kernel 1: partial sums (sum, sumsq per dim) of x -> part[16][NBLK]
// ---------------------------------------------------------------------------
__global__ void __launch_bounds__(TPB)
init_partials(const float* __restrict__ x, float* __restrict__ part)
{
    const int tid  = threadIdx.x;
    const int bid  = blockIdx.x;
    const int lane = tid & 63;
    const int wid  = tid >> 6;
    const size_t r0 = (size_t)bid * TPB + tid;

    __shared__ float lred[64];

    const float4* p0 = reinterpret_cast<const float4*>(x + r0 * 8);
    float4 a = p0[0], b4 = p0[1];
    float z0[8] = {a.x, a.y, a.z, a.w, b4.x, b4.y, b4.z, b4.w};

    float acc[16];
    #pragma unroll
    for (int j = 0; j < 8; ++j) {
        acc[j]     = z0[j];
        acc[8 + j] = z0[j] * z0[j];
    }
    #pragma unroll
    for (int d = 1; d < 64; d <<= 1) {
        #pragma unroll
        for (int j = 0; j < 16; ++j) acc[j] += __shfl_xor(acc[j], d, 64);
    }
    if (lane == 0) {
        #pragma unroll
        for (int j = 0; j < 16; ++j) lred[wid * 16 + j] = acc[j];
    }
    __syncthreads();
    if (tid < 16) {
        float s = lred[tid] + lred[16 + tid] + lred[32 + tid] + lred[48 + tid];
        part[tid * NBLK + bid] = s;
    }
}

// ---------------------------------------------------------------------------
// Kernel 2: one flow layer, 1 row per thread.
// ---------------------------------------------------------------------------
__global__ void __launch_bounds__(TPB)
layer_apply(const int L, const int last,
            const float* __restrict__ zin,  const float* __restrict__ ldin,
            float* __restrict__ zout,       float* __restrict__ ldout,
            const float* __restrict__ pin,  float* __restrict__ pout,
            const float* __restrict__ bvec, const float* __restrict__ logs,
            const float* __restrict__ log_gamma,
            const float* __restrict__ W1,   const float* __restrict__ b1,
            const float* __restrict__ W2,   const float* __restrict__ b2,
            const float* __restrict__ Wf,   const float* __restrict__ bf)
{
    const int tid  = threadIdx.x;
    const int bid  = blockIdx.x;
    const int lane = tid & 63;
    const int wid  = tid >> 6;
    const size_t r0 = (size_t)bid * TPB + tid;

    __shared__ float lred[64];

    // ---- stats: every block redundantly reduces the 16 x NBLK partials ----
    float tot[16];
    {
        float a16[16];
        #pragma unroll
        for (int j = 0; j < 16; ++j) {
            float s = 0.f;
            #pragma unroll
            for (int m = 0; m < NBLK / TPB; ++m)
                s += pin[j * NBLK + m * TPB + tid];
            a16[j] = s;
        }
        #pragma unroll
        for (int d = 1; d < 64; d <<= 1) {
            #pragma unroll
            for (int j = 0; j < 16; ++j) a16[j] += __shfl_xor(a16[j], d, 64);
        }
        if (lane == 0) {
            #pragma unroll
            for (int j = 0; j < 16; ++j) lred[wid * 16 + j] = a16[j];
        }
        __syncthreads();
        #pragma unroll
        for (int j = 0; j < 16; ++j)
            tot[j] = lred[j] + lred[16 + j] + lred[32 + j] + lred[48 + j];
        __syncthreads();   // everyone done reading lred before epilogue reuses it
    }

    const float invB = 1.0f / (float)B_ROWS;
    float es[8], beta[8];
    float sum_s = 0.f;
    #pragma unroll
    for (int j = 0; j < 8; ++j) {
        float m = tot[j] * invB;
        float q = tot[8 + j] * invB;
        float v = q - m * m;
        v = v < 0.f ? 0.f : v;
        float li = -(1.0f / 3.0f) * __logf(sqrtf(v) + 1e-6f);
        float s = logs[L * 8 + j] + li;
        s = s < -5.f ? -5.f : (s > 5.f ? 5.f : s);
        es[j]   = __expf(s);
        beta[j] = bvec[L * 8 + j] - m;
        sum_s  += s;
    }
    float gfac[4];
    #pragma unroll
    for (int j = 0; j < 4; ++j) {
        float lg = log_gamma[L * 4 + j];
        lg = lg < -5.f ? -5.f : (lg > 5.f ? 5.f : lg);
        gfac[j] = __expf(lg);
    }

    // ---- load row, actnorm ----
    float z[8];
    {
        const float4* p0 = reinterpret_cast<const float4*>(zin + r0 * 8);
        float4 a = p0[0], c = p0[1];
        z[0]=a.x; z[1]=a.y; z[2]=a.z; z[3]=a.w;
        z[4]=c.x; z[5]=c.y; z[6]=c.z; z[7]=c.w;
    }
    #pragma unroll
    for (int j = 0; j < 8; ++j)
        z[j] = (z[j] + beta[j]) * es[j];

    // ---- MLP (weights are uniform-address -> SGPR loads) ----
    const float* w1  = W1 + L * (4 * 32);
    const float* w2  = W2 + L * (32 * 32);
    const float* wf  = Wf + L * (32 * 8);
    const float* vb1 = b1 + L * 32;
    const float* vb2 = b2 + L * 32;
    const float* vbf = bf + L * 8;

    float h1[32];
    #pragma unroll
    for (int w = 0; w < 32; ++w) {
        float t = vb1[w];
        #pragma unroll
        for (int k = 0; k < 4; ++k)
            t += z[k] * w1[k * 32 + w];
        h1[w] = t > 0.f ? t : 0.f;
    }

    float h2[32];
    #pragma unroll
    for (int w = 0; w < 32; ++w) h2[w] = vb2[w];
    #pragma unroll
    for (int k = 0; k < 32; ++k) {
        float va = h1[k];
        #pragma unroll
        for (int w = 0; w < 32; ++w)
            h2[w] += va * w2[k * 32 + w];
    }
    #pragma unroll
    for (int w = 0; w < 32; ++w)
        h2[w] = h2[w] > 0.f ? h2[w] : 0.f;

    float h3[8];
    #pragma unroll
    for (int j = 0; j < 8; ++j) h3[j] = vbf[j];
    #pragma unroll
    for (int k = 0; k < 32; ++k) {
        float va = h2[k];
        #pragma unroll
        for (int j = 0; j < 8; ++j)
            h3[j] += va * wf[k * 8 + j];
    }

    // ---- coupling epilogue + permutation + next-layer partials ----
    float nacc[16];
    float ldv = ldin[r0];
    {
        float ldl = 0.f;
        float nz[8];
        #pragma unroll
        for (int j = 0; j < 4; ++j) {
            float sc = 0.6f * fast_tanh(h3[2 * j + 1]);
            float sh = gfac[j] * fast_tanh(h3[2 * j]);
            float z2 = z[4 + j];
            z2 = z2 + sc * z2 + sh;
            ldl += __logf(1.0f + sc);
            nz[3 - j] = z2;      // reversed: out[3-j] = z2_j
            nz[7 - j] = z[j];    // reversed: out[7-j] = z1_j
        }
        ldv += sum_s + ldl;
        #pragma unroll
        for (int j = 0; j < 8; ++j) {
            z[j] = nz[j];
            nacc[j]     = nz[j];
            nacc[8 + j] = nz[j] * nz[j];
        }
    }

    // ---- store z / ld ----
    {
        float4* p0 = reinterpret_cast<float4*>(zout + r0 * 8);
        float4 a, c;
        a.x=z[0]; a.y=z[1]; a.z=z[2]; a.w=z[3];
        c.x=z[4]; c.y=z[5]; c.z=z[6]; c.w=z[7];
        p0[0] = a; p0[1] = c;
    }
    ldout[r0] = ldv;

    if (!last) {
        #pragma unroll
        for (int d = 1; d < 64; d <<= 1) {
            #pragma unroll
            for (int j = 0; j < 16; ++j) nacc[j] += __shfl_xor(nacc[j], d, 64);
        }
        if (lane == 0) {
            #pragma unroll
            for (int j = 0; j < 16; ++j) lred[wid * 16 + j] = nacc[j];
        }
        __syncthreads();
        if (tid < 16) {
            float s = lred[tid] + lred[16 + tid] + lred[32 + tid] + lred[48 + tid];
            pout[tid * NBLK + bid] = s;
        }
    }
}

extern "C" void kernel_launch(void* const* d_in, const int* in_sizes, int n_in,
                              void* d_out, int out_size, void* d_ws, size_t ws_size,
                              hipStream_t stream) {
    const float* x      = (const float*)d_in[0];
    const float* logdet = (const float*)d_in[1];
    const float* bvec   = (const float*)d_in[2];
    const float* logs   = (const float*)d_in[3];
    const float* lg     = (const float*)d_in[4];
    const float* W1     = (const float*)d_in[5];
    const float* b1     = (const float*)d_in[6];
    const float* W2     = (const float*)d_in[7];
    const float* b2     = (const float*)d_in[8];
    const float* Wf     = (const float*)d_in[9];
    const float* bf     = (const float*)d_in[10];
    float* out = (float*)d_out;

    // workspace layout (floats): zA[B*8] | ldA[B] | part0[16*NBLK] | part1[16*NBLK]
    float* zA    = (float*)d_ws;
    float* ldA   = zA  + (size_t)B_ROWS * 8;
    float* part0 = ldA + B_ROWS;
    float* part1 = part0 + 16 * NBLK;

    float* out_z  = out;
    float* out_ld = out + (size_t)B_ROWS * 8;

    init_partials<<<NBLK, TPB, 0, stream>>>(x, part0);

    const float* zi  = x;
    const float* ldi = logdet;
    float* pbuf[2] = { part0, part1 };
    int buf = 0;
    for (int L = 0; L < 8; ++L) {
        float* zo  = (L & 1) ? out_z  : zA;    // L7 (odd) lands in out
        float* ldo = (L & 1) ? out_ld : ldA;
        int last = (L == 7);
        layer_apply<<<NBLK, TPB, 0, stream>>>(
            L, last, zi, ldi, zo, ldo, pbuf[buf], pbuf[buf ^ 1],
            bvec, logs, lg, W1, b1, W2, b2, Wf, bf);
        zi = zo; ldi = ldo; buf ^= 1;
    }
}

// Round 5
// 153.500 us; speedup vs baseline: 2.5897x; 1.7584x over previous
//
#include <hip/hip_runtime.h>

#define B_ROWS 262144
#define TPB 256
#define NBLK 1024   // B_ROWS / TPB, 1 row per thread

typedef _Float16 f16;
typedef __attribute__((ext_vector_type(2))) __fp16 fp16x2_t;  // cvt_pkrtz return type
typedef __attribute__((ext_vector_type(8))) _Float16 f16x8;
typedef __attribute__((ext_vector_type(4))) float f32x4;
typedef __attribute__((ext_vector_type(16))) float f32x16;

__device__ __forceinline__ float fast_tanh(float x) {
    float e = __expf(2.0f * x);
    return 1.0f - 2.0f * __builtin_amdgcn_rcpf(e + 1.0f);
}

// pack two f32 into one dword of 2 f16 (RTZ)
__device__ __forceinline__ float pkh(float a, float b) {
    fp16x2_t h = __builtin_amdgcn_cvt_pkrtz(a, b);
    return __builtin_bit_cast(float, h);
}
__device__ __forceinline__ f16x8 mk8(float a, float b, float c, float d) {
    f32x4 v = {a, b, c, d};
    return __builtin_bit_cast(f16x8, v);
}
__device__ __forceinline__ float sx32(float v) { return __shfl_xor(v, 32, 64); }

// ---------------------------------------------------------------------------
// Setup: pack W2 / Wf into MFMA A-fragment order (A = W^T), f16.
// t = ((L*2+kh)*64 + lane)*8 + j  holds  W[k = kh*16 + (lane>>5)*8 + j][lane&31]
// ---------------------------------------------------------------------------
__global__ void __launch_bounds__(TPB)
pack_weights(const float* __restrict__ W2, const float* __restrict__ Wf,
             f16* __restrict__ w2pk, f16* __restrict__ wfpk)
{
    int i = blockIdx.x * TPB + threadIdx.x;     // 0 .. 16383
    int which = i >> 13;
    int t  = i & 8191;
    int j  = t & 7;
    int ln = (t >> 3) & 63;
    int kh = (t >> 9) & 1;
    int L  = t >> 10;
    int k  = kh * 16 + ((ln >> 5) << 3) + j;
    if (which == 0) {
        w2pk[t] = (f16)W2[L * 1024 + k * 32 + (ln & 31)];
    } else {
        int row = ln & 31;
        wfpk[t] = (row < 8) ? (f16)Wf[L * 256 + k * 8 + row] : (f16)0.f;
    }
}

// ---------------------------------------------------------------------------
// Kernel 1: partial sums (sum, sumsq per dim) of x -> part[16][NBLK]
// ---------------------------------------------------------------------------
__global__ void __launch_bounds__(TPB)
init_partials(const float* __restrict__ x, float* __restrict__ part)
{
    const int tid  = threadIdx.x;
    const int bid  = blockIdx.x;
    const int lane = tid & 63;
    const int wid  = tid >> 6;
    const size_t r0 = (size_t)bid * TPB + tid;

    __shared__ float lred[64];

    const float4* p0 = reinterpret_cast<const float4*>(x + r0 * 8);
    float4 a = p0[0], b4 = p0[1];
    float z0[8] = {a.x, a.y, a.z, a.w, b4.x, b4.y, b4.z, b4.w};

    float acc[16];
    #pragma unroll
    for (int j = 0; j < 8; ++j) {
        acc[j]     = z0[j];
        acc[8 + j] = z0[j] * z0[j];
    }
    #pragma unroll
    for (int d = 1; d < 64; d <<= 1) {
        #pragma unroll
        for (int j = 0; j < 16; ++j) acc[j] += __shfl_xor(acc[j], d, 64);
    }
    if (lane == 0) {
        #pragma unroll
        for (int j = 0; j < 16; ++j) lred[wid * 16 + j] = acc[j];
    }
    __syncthreads();
    if (tid < 16) {
        float s = lred[tid] + lred[16 + tid] + lred[32 + tid] + lred[48 + tid];
        part[tid * NBLK + bid] = s;
    }
}

// ---------------------------------------------------------------------------
// Kernel 2: one flow layer, 1 row per thread, MFMA for W2 & Wf GEMMs.
// Per wave: 64 rows. C^T = W^T @ h^T via 32x32x16 f16 MFMA.
// ---------------------------------------------------------------------------
__global__ void __launch_bounds__(TPB)
layer_apply(const int L, const int last,
            const float* __restrict__ zin,  const float* __restrict__ ldin,
            float* __restrict__ zout,       float* __restrict__ ldout,
            const float* __restrict__ pin,  float* __restrict__ pout,
            const float* __restrict__ bvec, const float* __restrict__ logs,
            const float* __restrict__ log_gamma,
            const float* __restrict__ W1,   const float* __restrict__ b1,
            const float* __restrict__ b2,   const float* __restrict__ bf,
            const f16* __restrict__ w2pk,   const f16* __restrict__ wfpk)
{
    const int tid  = threadIdx.x;
    const int bid  = blockIdx.x;
    const int lane = tid & 63;
    const int wid  = tid >> 6;
    const bool lo  = lane < 32;
    const size_t r0 = (size_t)bid * TPB + tid;

    __shared__ float lred[64];

    // ---- stats: every block redundantly reduces the 16 x NBLK partials ----
    float tot[16];
    {
        float a16[16];
        #pragma unroll
        for (int j = 0; j < 16; ++j) {
            float s = 0.f;
            #pragma unroll
            for (int m = 0; m < NBLK / TPB; ++m)
                s += pin[j * NBLK + m * TPB + tid];
            a16[j] = s;
        }
        #pragma unroll
        for (int d = 1; d < 64; d <<= 1) {
            #pragma unroll
            for (int j = 0; j < 16; ++j) a16[j] += __shfl_xor(a16[j], d, 64);
        }
        if (lane == 0) {
            #pragma unroll
            for (int j = 0; j < 16; ++j) lred[wid * 16 + j] = a16[j];
        }
        __syncthreads();
        #pragma unroll
        for (int j = 0; j < 16; ++j)
            tot[j] = lred[j] + lred[16 + j] + lred[32 + j] + lred[48 + j];
        __syncthreads();
    }

    const float invB = 1.0f / (float)B_ROWS;
    float es[8], beta[8];
    float sum_s = 0.f;
    #pragma unroll
    for (int j = 0; j < 8; ++j) {
        float m = tot[j] * invB;
        float q = tot[8 + j] * invB;
        float v = q - m * m;
        v = v < 0.f ? 0.f : v;
        float li = -(1.0f / 3.0f) * __logf(sqrtf(v) + 1e-6f);
        float s = logs[L * 8 + j] + li;
        s = s < -5.f ? -5.f : (s > 5.f ? 5.f : s);
        es[j]   = __expf(s);
        beta[j] = bvec[L * 8 + j] - m;
        sum_s  += s;
    }
    float gfac[4];
    #pragma unroll
    for (int j = 0; j < 4; ++j) {
        float lg = log_gamma[L * 4 + j];
        lg = lg < -5.f ? -5.f : (lg > 5.f ? 5.f : lg);
        gfac[j] = __expf(lg);
    }

    // ---- load row, actnorm ----
    float z[8];
    {
        const float4* p0 = reinterpret_cast<const float4*>(zin + r0 * 8);
        float4 a = p0[0], c = p0[1];
        z[0]=a.x; z[1]=a.y; z[2]=a.z; z[3]=a.w;
        z[4]=c.x; z[5]=c.y; z[6]=c.z; z[7]=c.w;
    }
    #pragma unroll
    for (int j = 0; j < 8; ++j)
        z[j] = (z[j] + beta[j]) * es[j];

    // ---- W1: 4 -> 32, fp32 VALU (tiny) ----
    const float* w1  = W1 + L * (4 * 32);
    const float* vb1 = b1 + L * 32;
    const float* vb2 = b2 + L * 32;
    const float* vbf = bf + L * 8;

    float h1[32];
    #pragma unroll
    for (int w = 0; w < 32; ++w) {
        float t = vb1[w];
        #pragma unroll
        for (int k = 0; k < 4; ++k)
            t += z[k] * w1[k * 32 + w];
        h1[w] = t > 0.f ? t : 0.f;
    }

    // ---- pack h1 rows to f16 pairs; build W2 B-fragments ----
    float hp[16];
    #pragma unroll
    for (int c = 0; c < 16; ++c) hp[c] = pkh(h1[2 * c], h1[2 * c + 1]);
    float Sv[16];
    #pragma unroll
    for (int c = 0; c < 16; ++c) Sv[c] = sx32(hp[c]);

    // B_g_kh[p]: g0: lo?hp[kh*8+p]:Sv[kh*8+4+p];  g1: lo?Sv[kh*8+p]:hp[kh*8+4+p]
    f16x8 B00 = mk8(lo?hp[0]:Sv[4],  lo?hp[1]:Sv[5],  lo?hp[2]:Sv[6],  lo?hp[3]:Sv[7]);
    f16x8 B01 = mk8(lo?hp[8]:Sv[12], lo?hp[9]:Sv[13], lo?hp[10]:Sv[14],lo?hp[11]:Sv[15]);
    f16x8 B10 = mk8(lo?Sv[0]:hp[4],  lo?Sv[1]:hp[5],  lo?Sv[2]:hp[6],  lo?Sv[3]:hp[7]);
    f16x8 B11 = mk8(lo?Sv[8]:hp[12], lo?Sv[9]:hp[13], lo?Sv[10]:hp[14],lo?Sv[11]:hp[15]);

    // ---- W2 MFMA: D_g = W2^T @ h1^T (rows-group g) ----
    const f16x8* w2p = reinterpret_cast<const f16x8*>(w2pk);
    f16x8 A0 = w2p[(L * 2 + 0) * 64 + lane];
    f16x8 A1 = w2p[(L * 2 + 1) * 64 + lane];

    f32x16 d0 = {}, d1 = {};
    d0 = __builtin_amdgcn_mfma_f32_32x32x16_f16(A0, B00, d0, 0, 0, 0);
    d0 = __builtin_amdgcn_mfma_f32_32x32x16_f16(A1, B01, d0, 0, 0, 0);
    d1 = __builtin_amdgcn_mfma_f32_32x32x16_f16(A0, B10, d1, 0, 0, 0);
    d1 = __builtin_amdgcn_mfma_f32_32x32x16_f16(A1, B11, d1, 0, 0, 0);

    // ---- + b2, relu.  reg r holds w = (r&3) + 8*(r>>2) + 4*(lane>>5) ----
    float h2g0[16], h2g1[16];
    #pragma unroll
    for (int r = 0; r < 16; ++r) {
        int wlo = (r & 3) + 8 * (r >> 2);
        float bsel = lo ? vb2[wlo] : vb2[wlo + 4];
        float a = d0[r] + bsel; h2g0[r] = a > 0.f ? a : 0.f;
        float b = d1[r] + bsel; h2g1[r] = b > 0.f ? b : 0.f;
    }

    // ---- pack h2 -> f16 pairs (per-lane blocks), exchange halves ----
    float P0[8], P1[8], X0[8], X1[8];
    #pragma unroll
    for (int c = 0; c < 8; ++c) {
        P0[c] = pkh(h2g0[2 * c], h2g0[2 * c + 1]);
        P1[c] = pkh(h2g1[2 * c], h2g1[2 * c + 1]);
    }
    #pragma unroll
    for (int c = 0; c < 8; ++c) { X0[c] = sx32(P0[c]); X1[c] = sx32(P1[c]); }

    // Wf B-frag (g,kh), reg p:  lo ? (p<2 ? Pg[4kh+p] : Xg[4kh+p-2])
    //                              : (p<2 ? Xg[4kh+2+p] : Pg[4kh+p])
    f16x8 C00 = mk8(lo?P0[0]:X0[2], lo?P0[1]:X0[3], lo?X0[0]:P0[2], lo?X0[1]:P0[3]);
    f16x8 C01 = mk8(lo?P0[4]:X0[6], lo?P0[5]:X0[7], lo?X0[4]:P0[6], lo?X0[5]:P0[7]);
    f16x8 C10 = mk8(lo?P1[0]:X1[2], lo?P1[1]:X1[3], lo?X1[0]:P1[2], lo?X1[1]:P1[3]);
    f16x8 C11 = mk8(lo?P1[4]:X1[6], lo?P1[5]:X1[7], lo?X1[4]:P1[6], lo?X1[5]:P1[7]);

    // ---- Wf MFMA: D2_g = Wf^T(padded) @ h2^T ----
    const f16x8* wfp = reinterpret_cast<const f16x8*>(wfpk);
    f16x8 F0 = wfp[(L * 2 + 0) * 64 + lane];
    f16x8 F1 = wfp[(L * 2 + 1) * 64 + lane];

    f32x16 e0 = {}, e1 = {};
    e0 = __builtin_amdgcn_mfma_f32_32x32x16_f16(F0, C00, e0, 0, 0, 0);
    e0 = __builtin_amdgcn_mfma_f32_32x32x16_f16(F1, C01, e0, 0, 0, 0);
    e1 = __builtin_amdgcn_mfma_f32_32x32x16_f16(F0, C10, e1, 0, 0, 0);
    e1 = __builtin_amdgcn_mfma_f32_32x32x16_f16(F1, C11, e1, 0, 0, 0);

    // ---- gather own row's h3[0..7] ----
    float h3[8];
    #pragma unroll
    for (int r = 0; r < 4; ++r) {
        float s0 = sx32(e0[r]);
        float s1 = sx32(e1[r]);
        h3[r]     = (lo ? e0[r] : s1) + vbf[r];
        h3[r + 4] = (lo ? s0 : e1[r]) + vbf[r + 4];
    }

    // ---- coupling epilogue + permutation + next-layer partials ----
    float nacc[16];
    float ldv = ldin[r0];
    {
        float ldl = 0.f;
        float nz[8];
        #pragma unroll
        for (int j = 0; j < 4; ++j) {
            float sc = 0.6f * fast_tanh(h3[2 * j + 1]);
            float sh = gfac[j] * fast_tanh(h3[2 * j]);
            float z2 = z[4 + j];
            z2 = z2 + sc * z2 + sh;
            ldl += __logf(1.0f + sc);
            nz[3 - j] = z2;      // reversed: out[3-j] = z2_j
            nz[7 - j] = z[j];    // reversed: out[7-j] = z1_j
        }
        ldv += sum_s + ldl;
        #pragma unroll
        for (int j = 0; j < 8; ++j) {
            z[j] = nz[j];
            nacc[j]     = nz[j];
            nacc[8 + j] = nz[j] * nz[j];
        }
    }

    // ---- store z / ld ----
    {
        float4* p0 = reinterpret_cast<float4*>(zout + r0 * 8);
        float4 a, c;
        a.x=z[0]; a.y=z[1]; a.z=z[2]; a.w=z[3];
        c.x=z[4]; c.y=z[5]; c.z=z[6]; c.w=z[7];
        p0[0] = a; p0[1] = c;
    }
    ldout[r0] = ldv;

    if (!last) {
        #pragma unroll
        for (int d = 1; d < 64; d <<= 1) {
            #pragma unroll
            for (int j = 0; j < 16; ++j) nacc[j] += __shfl_xor(nacc[j], d, 64);
        }
        if (lane == 0) {
            #pragma unroll
            for (int j = 0; j < 16; ++j) lred[wid * 16 + j] = nacc[j];
        }
        __syncthreads();
        if (tid < 16) {
            float s = lred[tid] + lred[16 + tid] + lred[32 + tid] + lred[48 + tid];
            pout[tid * NBLK + bid] = s;
        }
    }
}

extern "C" void kernel_launch(void* const* d_in, const int* in_sizes, int n_in,
                              void* d_out, int out_size, void* d_ws, size_t ws_size,
                              hipStream_t stream) {
    const float* x      = (const float*)d_in[0];
    const float* logdet = (const float*)d_in[1];
    const float* bvec   = (const float*)d_in[2];
    const float* logs   = (const float*)d_in[3];
    const float* lg     = (const float*)d_in[4];
    const float* W1     = (const float*)d_in[5];
    const float* b1     = (const float*)d_in[6];
    const float* W2     = (const float*)d_in[7];
    const float* b2     = (const float*)d_in[8];
    const float* Wf     = (const float*)d_in[9];
    const float* bf     = (const float*)d_in[10];
    float* out = (float*)d_out;

    // ws layout (floats): zA[B*8] | ldA[B] | part0[16*NBLK] | part1[16*NBLK]
    //                     | w2pk[8192 f16] | wfpk[8192 f16]
    float* zA    = (float*)d_ws;
    float* ldA   = zA  + (size_t)B_ROWS * 8;
    float* part0 = ldA + B_ROWS;
    float* part1 = part0 + 16 * NBLK;
    f16*   w2pk  = (f16*)(part1 + 16 * NBLK);
    f16*   wfpk  = w2pk + 8192;

    float* out_z  = out;
    float* out_ld = out + (size_t)B_ROWS * 8;

    pack_weights<<<64, TPB, 0, stream>>>(W2, Wf, w2pk, wfpk);
    init_partials<<<NBLK, TPB, 0, stream>>>(x, part0);

    const float* zi  = x;
    const float* ldi = logdet;
    float* pbuf[2] = { part0, part1 };
    int buf = 0;
    for (int L = 0; L < 8; ++L) {
        float* zo  = (L & 1) ? out_z  : zA;    // L7 (odd) lands in out
        float* ldo = (L & 1) ? out_ld : ldA;
        int last = (L == 7);
        layer_apply<<<NBLK, TPB, 0, stream>>>(
            L, last, zi, ldi, zo, ldo, pbuf[buf], pbuf[buf ^ 1],
            bvec, logs, lg, W1, b1, b2, bf, w2pk, wfpk);
        zi = zo; ldi = ldo; buf ^= 1;
    }
}